// Round 1
// baseline (4776.900 us; speedup 1.0000x reference)
//
#include <hip/hip_runtime.h>
#include <math.h>

// =====================================================================
// ViT discriminator forward (fp32 baseline, round 1)
// R1 plan: correct fp32 everywhere. GEMMs: 128x128 tile, 8x8 micro,
// single-LDS-buffer prefetch. Attention: fused flash-style with
// d2 = |q|^2+|k|^2-2qk, sqrt, online softmax (no SxS materialization).
// Next rounds: bf16 MFMA GEMMs (m97 template), MFMA attention.
// =====================================================================

#define BATCH   16
#define TSEQ    1025
#define DMODEL  384
#define NHEAD   4
#define HDIM    96
#define NBLK    3
#define FFDIM   1536
#define IMGSZ   512
#define NPATCHI 1024                 // patches per image (32x32)
#define MROWS   (BATCH*TSEQ)         // 16400
#define MPATCH  (BATCH*NPATCHI)      // 16384
#define KPE     768                  // CIN*16*16
#define LDQKV   1152                 // q|k|v concatenated row stride
#define ATT_SCALE 0.10206207261596577f  // 1/sqrt(96)

// ---------------------------------------------------------------------
// Generic tiled GEMM: C[M,N] = A[M,K] @ B[K,N] (+bias)(+relu)(+res)
// BT=true: B given as [N,K] row-major (used for conv_w).
// EPI: 0 = (+bias), 1 = relu(+bias), 2 = res + (+bias)
// ---------------------------------------------------------------------
template<int EPI, bool BT>
__global__ __launch_bounds__(256, 2) void gemm_k(
    const float* __restrict__ A, const float* __restrict__ Bm,
    const float* __restrict__ bias, const float* res,
    float* C, int M, int N, int K)
{
  __shared__ float As[8][128];
  __shared__ float Bs[8][128];
  const int tid  = threadIdx.x;
  const int row0 = blockIdx.x * 128;
  const int col0 = blockIdx.y * 128;
  const int lrow = tid >> 1;          // 0..127
  const int lcol = (tid & 1) * 4;     // 0 or 4
  const int brow = tid >> 5;          // 0..7
  const int bcol = (tid & 31) * 4;    // 0..124
  const int tm4  = (tid >> 4) * 4;
  const int tn4  = (tid & 15) * 4;

  float4 av = make_float4(0.f, 0.f, 0.f, 0.f);
  float4 bv = make_float4(0.f, 0.f, 0.f, 0.f);
  {
    const int gr = row0 + lrow;
    if (gr < M) av = *(const float4*)&A[(size_t)gr * K + lcol];
    if (BT) {
      const int gn = col0 + lrow;
      if (gn < N) bv = *(const float4*)&Bm[(size_t)gn * K + lcol];
    } else {
      bv = *(const float4*)&Bm[(size_t)brow * N + col0 + bcol];
    }
  }
  float acc[8][8];
#pragma unroll
  for (int i = 0; i < 8; ++i)
#pragma unroll
    for (int j = 0; j < 8; ++j) acc[i][j] = 0.f;

  for (int k0 = 0; k0 < K; k0 += 8) {
    As[lcol + 0][lrow] = av.x; As[lcol + 1][lrow] = av.y;
    As[lcol + 2][lrow] = av.z; As[lcol + 3][lrow] = av.w;
    if (BT) {
      Bs[lcol + 0][lrow] = bv.x; Bs[lcol + 1][lrow] = bv.y;
      Bs[lcol + 2][lrow] = bv.z; Bs[lcol + 3][lrow] = bv.w;
    } else {
      *(float4*)&Bs[brow][bcol] = bv;
    }
    __syncthreads();
    if (k0 + 8 < K) {   // prefetch next k-slice while computing this one
      const int k1 = k0 + 8;
      const int gr = row0 + lrow;
      av = make_float4(0.f, 0.f, 0.f, 0.f);
      if (gr < M) av = *(const float4*)&A[(size_t)gr * K + k1 + lcol];
      if (BT) {
        const int gn = col0 + lrow;
        bv = make_float4(0.f, 0.f, 0.f, 0.f);
        if (gn < N) bv = *(const float4*)&Bm[(size_t)gn * K + k1 + lcol];
      } else {
        bv = *(const float4*)&Bm[(size_t)(k1 + brow) * N + col0 + bcol];
      }
    }
#pragma unroll
    for (int kk = 0; kk < 8; ++kk) {
      const float4 a0 = *(const float4*)&As[kk][tm4];
      const float4 a1 = *(const float4*)&As[kk][tm4 + 64];
      const float4 b0 = *(const float4*)&Bs[kk][tn4];
      const float4 b1 = *(const float4*)&Bs[kk][tn4 + 64];
      const float a[8] = {a0.x, a0.y, a0.z, a0.w, a1.x, a1.y, a1.z, a1.w};
      const float b[8] = {b0.x, b0.y, b0.z, b0.w, b1.x, b1.y, b1.z, b1.w};
#pragma unroll
      for (int i = 0; i < 8; ++i)
#pragma unroll
        for (int j = 0; j < 8; ++j)
          acc[i][j] = fmaf(a[i], b[j], acc[i][j]);
    }
    __syncthreads();
  }

#pragma unroll
  for (int i = 0; i < 8; ++i) {
    const int gr = row0 + tm4 + ((i < 4) ? i : (60 + i));
    if (gr >= M) continue;
#pragma unroll
    for (int jh = 0; jh < 2; ++jh) {
      const int gc = col0 + tn4 + jh * 64;
      float r0 = acc[i][jh * 4 + 0], r1 = acc[i][jh * 4 + 1];
      float r2 = acc[i][jh * 4 + 2], r3 = acc[i][jh * 4 + 3];
      if (bias != nullptr) {
        r0 += bias[gc + 0]; r1 += bias[gc + 1];
        r2 += bias[gc + 2]; r3 += bias[gc + 3];
      }
      if (EPI == 1) {
        r0 = fmaxf(r0, 0.f); r1 = fmaxf(r1, 0.f);
        r2 = fmaxf(r2, 0.f); r3 = fmaxf(r3, 0.f);
      }
      if (EPI == 2) {
        const float4 rv = *(const float4*)&res[(size_t)gr * N + gc];
        r0 += rv.x; r1 += rv.y; r2 += rv.z; r3 += rv.w;
      }
      *(float4*)&C[(size_t)gr * N + gc] = make_float4(r0, r1, r2, r3);
    }
  }
}

// ---------------------------------------------------------------------
// im2col for patch embedding: Ai[16384][768]
// ---------------------------------------------------------------------
__global__ __launch_bounds__(256) void im2col_k(
    const float* __restrict__ x, float* __restrict__ Ai)
{
  const int i = blockIdx.x * 256 + threadIdx.x;       // over float4s
  const int row = i / 192;
  const int k4  = (i - row * 192) * 4;
  const int b   = row >> 10;
  const int pidx = row & 1023;
  const int py = pidx >> 5, px = pidx & 31;
  const int cc = k4 >> 8;
  const int rem = k4 & 255;
  const int p = rem >> 4, q = rem & 15;
  const float* src = x + ((size_t)((b * 3 + cc) * IMGSZ + py * 16 + p)) * IMGSZ
                       + px * 16 + q;
  *(float4*)&Ai[(size_t)i * 4] = *(const float4*)src;
}

// ---------------------------------------------------------------------
// h[b,t,:] = (t==0 ? cls : pe[b,t-1]) + pos[t]
// ---------------------------------------------------------------------
__global__ __launch_bounds__(256) void embed_k(
    const float* __restrict__ pe, const float* __restrict__ cls,
    const float* __restrict__ pos, float* __restrict__ h)
{
  const int i = blockIdx.x * 256 + threadIdx.x;       // over float4s
  const int row = i / 96;
  const int d4 = (i - row * 96) * 4;
  const int b = row / TSEQ;
  const int t = row - b * TSEQ;
  const float4 po = *(const float4*)&pos[(size_t)t * DMODEL + d4];
  float4 r;
  if (t == 0) {
    const float4 cv = *(const float4*)&cls[d4];
    r = make_float4(cv.x + po.x, cv.y + po.y, cv.z + po.z, cv.w + po.w);
  } else {
    const float4 pv = *(const float4*)&pe[((size_t)(b * NPATCHI + t - 1)) * DMODEL + d4];
    r = make_float4(pv.x + po.x, pv.y + po.y, pv.z + po.z, pv.w + po.w);
  }
  *(float4*)&h[(size_t)row * DMODEL + d4] = r;
}

// ---------------------------------------------------------------------
// concat wq|wk|wv -> wcat[384][1152]
// ---------------------------------------------------------------------
__global__ __launch_bounds__(256) void concat_w_k(
    const float* __restrict__ wq, const float* __restrict__ wk,
    const float* __restrict__ wv, float* __restrict__ wcat)
{
  const int i = blockIdx.x * 256 + threadIdx.x;       // over float4s
  const int k = i / 288;
  const int j4 = (i - k * 288) * 4;
  const float* src;
  if (j4 < 384)       src = &wq[(size_t)k * 384 + j4];
  else if (j4 < 768)  src = &wk[(size_t)k * 384 + j4 - 384];
  else                src = &wv[(size_t)k * 384 + j4 - 768];
  *(float4*)&wcat[(size_t)k * 1152 + j4] = *(const float4*)src;
}

// ---------------------------------------------------------------------
// LayerNorm over D=384. One wave per row, 4 rows per block.
// ---------------------------------------------------------------------
__global__ __launch_bounds__(256) void ln_k(
    const float* __restrict__ in, const float* __restrict__ sc,
    const float* __restrict__ bi, float* __restrict__ out)
{
  const int w = threadIdx.x >> 6, lane = threadIdx.x & 63;
  const int row = blockIdx.x * 4 + w;
  const float* r = in + (size_t)row * DMODEL;
  float v[6], sum = 0.f, ss = 0.f;
#pragma unroll
  for (int j = 0; j < 6; ++j) {
    const float xv = r[lane + 64 * j];
    v[j] = xv; sum += xv; ss += xv * xv;
  }
#pragma unroll
  for (int m = 1; m < 64; m <<= 1) {
    sum += __shfl_xor(sum, m, 64);
    ss  += __shfl_xor(ss,  m, 64);
  }
  const float mean = sum * (1.f / 384.f);
  const float var  = ss * (1.f / 384.f) - mean * mean;
  const float rstd = rsqrtf(var + 1e-5f);
  float* o = out + (size_t)row * DMODEL;
#pragma unroll
  for (int j = 0; j < 6; ++j) {
    const int col = lane + 64 * j;
    o[col] = (v[j] - mean) * rstd * sc[col] + bi[col];
  }
}

// ---------------------------------------------------------------------
// per-(b,h,t) sum of squares of q and k rows (from concatenated qkv)
// ---------------------------------------------------------------------
__global__ __launch_bounds__(256) void sumsq_k(
    const float* __restrict__ qkv, float* __restrict__ sq2,
    float* __restrict__ sk2)
{
  const int w = threadIdx.x >> 6, lane = threadIdx.x & 63;
  const int row = blockIdx.x * 4 + w;                 // b*T + t
  const int h = lane >> 4, lg = lane & 15;
  const float* q = qkv + (size_t)row * LDQKV + h * HDIM;
  float s1 = 0.f, s2 = 0.f;
#pragma unroll
  for (int j = 0; j < 6; ++j) {
    const float a = q[lg + 16 * j];
    const float c = q[384 + lg + 16 * j];
    s1 += a * a; s2 += c * c;
  }
#pragma unroll
  for (int m = 1; m < 16; m <<= 1) {
    s1 += __shfl_xor(s1, m, 64);
    s2 += __shfl_xor(s2, m, 64);
  }
  if (lg == 0) {
    const int b = row / TSEQ, t = row - b * TSEQ;
    sq2[((size_t)b * NHEAD + h) * TSEQ + t] = s1;
    sk2[((size_t)b * NHEAD + h) * TSEQ + t] = s2;
  }
}

// ---------------------------------------------------------------------
// Fused distance attention (flash-style, online softmax).
// grid (33 q-tiles, B*NH). 256 thr: qr=tid/8 (32 rows), kg=tid%8.
// Each thread: full q row (96 regs), 8 keys/chunk strided by 8,
// 12-dim slice of O.
// ---------------------------------------------------------------------
__global__ __launch_bounds__(256) void attn_k(
    const float* __restrict__ qkv, const float* __restrict__ sq2,
    const float* __restrict__ sk2, float* __restrict__ Obuf)
{
  __shared__ float Ks[64][100];   // padded: rows land on distinct banks
  __shared__ float Vs[64][100];
  __shared__ float Ps[32][66];
  __shared__ float sks[64];
  const int qt = blockIdx.x, bh = blockIdx.y;
  const int bb = bh >> 2, hh = bh & 3;
  const int tid = threadIdx.x;
  const int qr = tid >> 3, kg = tid & 7;
  const int qrow = qt * 32 + qr;

  float qv[96];
  float sqv = 0.f;
  if (qrow < TSEQ) {
    const float* qsrc = qkv + ((size_t)(bb * TSEQ + qrow)) * LDQKV + hh * HDIM;
#pragma unroll
    for (int u = 0; u < 24; ++u) {
      const float4 t4 = *(const float4*)&qsrc[u * 4];
      qv[u * 4 + 0] = t4.x; qv[u * 4 + 1] = t4.y;
      qv[u * 4 + 2] = t4.z; qv[u * 4 + 3] = t4.w;
    }
    sqv = sq2[((size_t)bb * NHEAD + hh) * TSEQ + qrow];
  } else {
#pragma unroll
    for (int u = 0; u < 96; ++u) qv[u] = 0.f;
  }

  float mrun = -INFINITY, lrun = 0.f;
  float oa[12];
#pragma unroll
  for (int d = 0; d < 12; ++d) oa[d] = 0.f;

  const int kr = tid >> 2, part = tid & 3;
  for (int c = 0; c < 17; ++c) {
    // ---- stage K,V chunk ----
    const int krow = c * 64 + kr;
    if (krow < TSEQ) {
      const float* ks = qkv + ((size_t)(bb * TSEQ + krow)) * LDQKV + 384
                        + hh * HDIM + part * 24;
      const float* vs = ks + 384;
#pragma unroll
      for (int u = 0; u < 6; ++u) {
        *(float4*)&Ks[kr][part * 24 + u * 4] = *(const float4*)&ks[u * 4];
        *(float4*)&Vs[kr][part * 24 + u * 4] = *(const float4*)&vs[u * 4];
      }
    } else {
#pragma unroll
      for (int u = 0; u < 6; ++u) {
        *(float4*)&Ks[kr][part * 24 + u * 4] = make_float4(0.f, 0.f, 0.f, 0.f);
        *(float4*)&Vs[kr][part * 24 + u * 4] = make_float4(0.f, 0.f, 0.f, 0.f);
      }
    }
    if (tid < 64) {
      const int gk = c * 64 + tid;
      sks[tid] = (gk < TSEQ) ? sk2[((size_t)bb * NHEAD + hh) * TSEQ + gk] : 0.f;
    }
    __syncthreads();

    // ---- scores for 8 keys (strided by 8: conflict-free rows) ----
    float scv[8];
    float cmax = -INFINITY;
#pragma unroll
    for (int j = 0; j < 8; ++j) {
      const int key = kg + 8 * j;
      float d0 = 0.f, d1 = 0.f, d2a = 0.f, d3 = 0.f;
#pragma unroll
      for (int u = 0; u < 24; ++u) {
        const float4 kk4 = *(const float4*)&Ks[key][u * 4];
        d0  = fmaf(qv[u * 4 + 0], kk4.x, d0);
        d1  = fmaf(qv[u * 4 + 1], kk4.y, d1);
        d2a = fmaf(qv[u * 4 + 2], kk4.z, d2a);
        d3  = fmaf(qv[u * 4 + 3], kk4.w, d3);
      }
      const float dot = (d0 + d1) + (d2a + d3);
      const float dist2 = sqv + sks[key] - 2.f * dot;
      float s = sqrtf(fmaxf(dist2, 0.f)) * ATT_SCALE;
      if (c * 64 + key >= TSEQ) s = -INFINITY;
      scv[j] = s;
      cmax = fmaxf(cmax, s);
    }
#pragma unroll
    for (int m = 1; m < 8; m <<= 1) cmax = fmaxf(cmax, __shfl_xor(cmax, m, 64));
    const float mn = fmaxf(mrun, cmax);           // >= 0: every chunk has a valid key
    const float f = expf(mrun - mn);              // first chunk: exp(-inf)=0
    float psum = 0.f;
#pragma unroll
    for (int j = 0; j < 8; ++j) {
      const float p = expf(scv[j] - mn);          // -inf -> 0
      scv[j] = p; psum += p;
    }
#pragma unroll
    for (int m = 1; m < 8; m <<= 1) psum += __shfl_xor(psum, m, 64);
    lrun = lrun * f + psum;
    mrun = mn;
#pragma unroll
    for (int d = 0; d < 12; ++d) oa[d] *= f;
#pragma unroll
    for (int j = 0; j < 8; ++j) Ps[qr][kg + 8 * j] = scv[j];
    __syncthreads();

    // ---- PV: each thread accumulates its 12-dim slice over 64 keys ----
    const int dof = kg * 12;
#pragma unroll
    for (int key = 0; key < 64; ++key) {
      const float p = Ps[qr][key];
      const float4 v0 = *(const float4*)&Vs[key][dof];
      const float4 v1 = *(const float4*)&Vs[key][dof + 4];
      const float4 v2 = *(const float4*)&Vs[key][dof + 8];
      oa[0]  = fmaf(p, v0.x, oa[0]);  oa[1]  = fmaf(p, v0.y, oa[1]);
      oa[2]  = fmaf(p, v0.z, oa[2]);  oa[3]  = fmaf(p, v0.w, oa[3]);
      oa[4]  = fmaf(p, v1.x, oa[4]);  oa[5]  = fmaf(p, v1.y, oa[5]);
      oa[6]  = fmaf(p, v1.z, oa[6]);  oa[7]  = fmaf(p, v1.w, oa[7]);
      oa[8]  = fmaf(p, v2.x, oa[8]);  oa[9]  = fmaf(p, v2.y, oa[9]);
      oa[10] = fmaf(p, v2.z, oa[10]); oa[11] = fmaf(p, v2.w, oa[11]);
    }
    __syncthreads();
  }

  if (qrow < TSEQ) {
    const float inv = 1.f / lrun;
    float* o = Obuf + ((size_t)(bb * TSEQ + qrow)) * DMODEL + hh * HDIM + kg * 12;
#pragma unroll
    for (int d = 0; d < 12; ++d) o[d] = oa[d] * inv;
  }
}

// ---------------------------------------------------------------------
// Final LN (cls rows only) + projection + log_softmax + NLL loss
// out[0..31] = logits (16x2), out[32] = loss. Single block.
// ---------------------------------------------------------------------
__global__ __launch_bounds__(256) void head_k(
    const float* __restrict__ h, const float* __restrict__ gs,
    const float* __restrict__ gb, const float* __restrict__ pw,
    const float* __restrict__ pb, const int* __restrict__ tgt,
    float* __restrict__ out)
{
  __shared__ float lg[BATCH][2];
  const int w = threadIdx.x >> 6, lane = threadIdx.x & 63;
  for (int b = w; b < BATCH; b += 4) {
    const float* r = h + (size_t)b * TSEQ * DMODEL;   // t = 0 row
    float v[6], sum = 0.f, ss = 0.f;
#pragma unroll
    for (int j = 0; j < 6; ++j) {
      const float xv = r[lane + 64 * j];
      v[j] = xv; sum += xv; ss += xv * xv;
    }
#pragma unroll
    for (int m = 1; m < 64; m <<= 1) {
      sum += __shfl_xor(sum, m, 64);
      ss  += __shfl_xor(ss,  m, 64);
    }
    const float mean = sum * (1.f / 384.f);
    const float var  = ss * (1.f / 384.f) - mean * mean;
    const float rstd = rsqrtf(var + 1e-5f);
    float l0 = 0.f, l1 = 0.f;
#pragma unroll
    for (int j = 0; j < 6; ++j) {
      const int col = lane + 64 * j;
      const float hnv = (v[j] - mean) * rstd * gs[col] + gb[col];
      l0 = fmaf(hnv, pw[col * 2 + 0], l0);
      l1 = fmaf(hnv, pw[col * 2 + 1], l1);
    }
#pragma unroll
    for (int m = 1; m < 64; m <<= 1) {
      l0 += __shfl_xor(l0, m, 64);
      l1 += __shfl_xor(l1, m, 64);
    }
    if (lane == 0) { lg[b][0] = l0 + pb[0]; lg[b][1] = l1 + pb[1]; }
  }
  __syncthreads();
  if (threadIdx.x < 32)
    out[threadIdx.x] = lg[threadIdx.x >> 1][threadIdx.x & 1];
  if (threadIdx.x == 0) {
    float acc = 0.f;
    for (int b = 0; b < BATCH; ++b) {
      const float a = lg[b][0], c = lg[b][1];
      const float mx = fmaxf(a, c);
      const float lse = mx + logf(expf(a - mx) + expf(c - mx));
      const float lp = ((tgt[b] == 0) ? a : c) - lse;
      acc += lp;
    }
    out[32] = -acc * (1.f / BATCH);
  }
}

// ---------------------------------------------------------------------
extern "C" void kernel_launch(void* const* d_in, const int* in_sizes, int n_in,
                              void* d_out, int out_size, void* d_ws, size_t ws_size,
                              hipStream_t stream)
{
  const float* x        = (const float*)d_in[0];
  const int*   targets  = (const int*)  d_in[1];
  const float* conv_w   = (const float*)d_in[2];
  const float* conv_b   = (const float*)d_in[3];
  const float* cls_tok  = (const float*)d_in[4];
  const float* pos_emb  = (const float*)d_in[5];
  const float* ln1_s    = (const float*)d_in[6];
  const float* ln1_b    = (const float*)d_in[7];
  const float* ln2_s    = (const float*)d_in[8];
  const float* ln2_b    = (const float*)d_in[9];
  const float* wq       = (const float*)d_in[10];
  const float* wk       = (const float*)d_in[11];
  const float* wv       = (const float*)d_in[12];
  const float* wo       = (const float*)d_in[13];
  const float* bo       = (const float*)d_in[14];
  const float* w1       = (const float*)d_in[15];
  const float* b1       = (const float*)d_in[16];
  const float* w2       = (const float*)d_in[17];
  const float* b2       = (const float*)d_in[18];
  const float* lnf_s    = (const float*)d_in[19];
  const float* lnf_b    = (const float*)d_in[20];
  const float* proj_w   = (const float*)d_in[21];
  const float* proj_b   = (const float*)d_in[22];

  float* ws = (float*)d_ws;
  const size_t SZ = (size_t)MROWS * DMODEL;           // 6,297,600
  float* h      = ws;
  float* hn     = ws + SZ;
  float* bufQKV = ws + 2 * SZ;                        // 16400*1152 = 18,892,800
  float* bufO   = bufQKV + (size_t)MROWS * LDQKV;     // 6,297,600
  float* sq2    = bufO + SZ;
  float* sk2    = sq2 + (size_t)BATCH * NHEAD * TSEQ; // 65,600 each
  float* wcat   = sk2 + (size_t)BATCH * NHEAD * TSEQ; // 442,368
  // aliases (disjoint in time):
  float* Ai  = bufQKV;   // im2col buffer (12.58M floats <= 18.9M)
  float* pe  = bufO;     // patch GEMM output (6.29M <= 6.30M)
  float* ffb = bufQKV;   // MLP hidden (25.19M = QKV+O regions exactly)

  const size_t need = (2 * SZ + (size_t)MROWS * LDQKV + SZ
                       + 2 * (size_t)BATCH * NHEAD * TSEQ + 442368) * sizeof(float);
  if (ws_size < need) return;   // harness will flag wrong output

  // ---- patch embedding ----
  im2col_k<<<12288, 256, 0, stream>>>(x, Ai);
  gemm_k<0, true><<<dim3(128, 3), 256, 0, stream>>>(
      Ai, conv_w, conv_b, nullptr, pe, MPATCH, DMODEL, KPE);
  embed_k<<<6150, 256, 0, stream>>>(pe, cls_tok, pos_emb, h);

  // ---- transformer blocks ----
  for (int i = 0; i < NBLK; ++i) {
    ln_k<<<4100, 256, 0, stream>>>(h, ln1_s + i * DMODEL, ln1_b + i * DMODEL, hn);
    concat_w_k<<<432, 256, 0, stream>>>(
        wq + (size_t)i * DMODEL * DMODEL, wk + (size_t)i * DMODEL * DMODEL,
        wv + (size_t)i * DMODEL * DMODEL, wcat);
    gemm_k<0, false><<<dim3(129, 9), 256, 0, stream>>>(
        hn, wcat, nullptr, nullptr, bufQKV, MROWS, LDQKV, DMODEL);
    sumsq_k<<<4100, 256, 0, stream>>>(bufQKV, sq2, sk2);
    attn_k<<<dim3(33, BATCH * NHEAD), 256, 0, stream>>>(bufQKV, sq2, sk2, bufO);
    gemm_k<2, false><<<dim3(129, 3), 256, 0, stream>>>(
        bufO, wo + (size_t)i * DMODEL * DMODEL, bo + i * DMODEL, h, h,
        MROWS, DMODEL, DMODEL);
    ln_k<<<4100, 256, 0, stream>>>(h, ln2_s + i * DMODEL, ln2_b + i * DMODEL, hn);
    gemm_k<1, false><<<dim3(129, 12), 256, 0, stream>>>(
        hn, w1 + (size_t)i * DMODEL * FFDIM, b1 + i * FFDIM, nullptr, ffb,
        MROWS, FFDIM, DMODEL);
    gemm_k<2, false><<<dim3(129, 3), 256, 0, stream>>>(
        ffb, w2 + (size_t)i * DMODEL * FFDIM, b2 + i * DMODEL, h, h,
        MROWS, DMODEL, FFDIM);
  }

  // ---- head: final LN (cls only) + proj + loss ----
  head_k<<<1, 256, 0, stream>>>(h, lnf_s, lnf_b, proj_w, proj_b, targets,
                                (float*)d_out);
}

// Round 2
// 1350.521 us; speedup vs baseline: 3.5371x; 3.5371x over previous
//
#include <hip/hip_runtime.h>
#include <math.h>

// =====================================================================
// ViT discriminator forward — round 2: bf16 MFMA everywhere heavy.
// GEMM: 128x128 tile, 16x16x32 bf16 MFMA, double-buffered reg-staged
// LDS (pad 40 -> 2-way-free bank pattern). Attention: flash-style MFMA
// QK^T + online softmax + P(bf16,LDS) V(transposed at staging) MFMA.
// Residual h stays fp32; epilogues emit bf16 for GEMM consumers.
// =====================================================================

#define BATCH   16
#define TSEQ    1025
#define DMODEL  384
#define NHEAD   4
#define HDIM    96
#define NBLK    3
#define FFDIM   1536
#define IMGSZ   512
#define NPATCHI 1024
#define MROWS   (BATCH*TSEQ)      // 16400
#define MPATCH  (BATCH*NPATCHI)   // 16384
#define KPE     768
#define ATT_SCALE 0.10206207261596577f  // 1/sqrt(96)

typedef __attribute__((ext_vector_type(8))) __bf16 bf16x8;
typedef __attribute__((ext_vector_type(4))) float  f32x4;

__device__ __forceinline__ f32x4 fzero4() {
  f32x4 v; v[0] = 0.f; v[1] = 0.f; v[2] = 0.f; v[3] = 0.f; return v;
}
__device__ __forceinline__ bf16x8 bzero8() {
  bf16x8 v;
#pragma unroll
  for (int j = 0; j < 8; ++j) v[j] = (__bf16)0.f;
  return v;
}

// ---------------------------------------------------------------------
// bf16 MFMA GEMM: C[M,N] = A[M,K] @ Bt[N,K]^T, K % 32 == 0, N % 128 == 0.
// EPI bits: 1=+bias, 2=relu, 4=+res(fp32), 8=write Cf(fp32), 16=write Cb(bf16)
// ---------------------------------------------------------------------
template<int EPI>
__global__ __launch_bounds__(256, 2) void mgemm_k(
    const __bf16* __restrict__ A, const __bf16* __restrict__ Bt,
    const float* __restrict__ bias, const float* __restrict__ res,
    float* __restrict__ Cf, __bf16* __restrict__ Cb, int M, int N, int K)
{
  __shared__ __bf16 Al[2][128][40];   // pad 32->40 (80B rows, 16B-aligned)
  __shared__ __bf16 Bl[2][128][40];
  const int tid = threadIdx.x;
  const int lane = tid & 63;
  const int w = tid >> 6;
  const int wr = w >> 1, wc = w & 1;
  const int l15 = lane & 15, g = lane >> 4;
  const int row0 = blockIdx.x * 128, col0 = blockIdx.y * 128;
  const int srow = tid >> 1, soff = (tid & 1) * 16;
  int ar = row0 + srow; if (ar > M - 1) ar = M - 1;
  const __bf16* ap = A + (size_t)ar * K + soff;
  const __bf16* bp = Bt + (size_t)(col0 + srow) * K + soff;

  f32x4 acc[4][4];
#pragma unroll
  for (int i = 0; i < 4; ++i)
#pragma unroll
    for (int j = 0; j < 4; ++j) acc[i][j] = fzero4();

  const int nk = K >> 5;
  bf16x8 ra0 = *(const bf16x8*)ap;
  bf16x8 ra1 = *(const bf16x8*)(ap + 8);
  bf16x8 rb0 = *(const bf16x8*)bp;
  bf16x8 rb1 = *(const bf16x8*)(bp + 8);
  *(bf16x8*)&Al[0][srow][soff]     = ra0;
  *(bf16x8*)&Al[0][srow][soff + 8] = ra1;
  *(bf16x8*)&Bl[0][srow][soff]     = rb0;
  *(bf16x8*)&Bl[0][srow][soff + 8] = rb1;
  __syncthreads();
  int cur = 0;
  for (int kt = 0; kt < nk; ++kt) {
    const bool pf = (kt + 1 < nk);
    if (pf) {
      const __bf16* a2 = ap + (size_t)(kt + 1) * 32;
      const __bf16* b2 = bp + (size_t)(kt + 1) * 32;
      ra0 = *(const bf16x8*)a2; ra1 = *(const bf16x8*)(a2 + 8);
      rb0 = *(const bf16x8*)b2; rb1 = *(const bf16x8*)(b2 + 8);
    }
    bf16x8 af[4], bfr[4];
#pragma unroll
    for (int mi = 0; mi < 4; ++mi)
      af[mi] = *(const bf16x8*)&Al[cur][wr * 64 + mi * 16 + l15][g * 8];
#pragma unroll
    for (int ni = 0; ni < 4; ++ni)
      bfr[ni] = *(const bf16x8*)&Bl[cur][wc * 64 + ni * 16 + l15][g * 8];
#pragma unroll
    for (int mi = 0; mi < 4; ++mi)
#pragma unroll
      for (int ni = 0; ni < 4; ++ni)
        acc[mi][ni] = __builtin_amdgcn_mfma_f32_16x16x32_bf16(
            af[mi], bfr[ni], acc[mi][ni], 0, 0, 0);
    if (pf) {
      *(bf16x8*)&Al[cur ^ 1][srow][soff]     = ra0;
      *(bf16x8*)&Al[cur ^ 1][srow][soff + 8] = ra1;
      *(bf16x8*)&Bl[cur ^ 1][srow][soff]     = rb0;
      *(bf16x8*)&Bl[cur ^ 1][srow][soff + 8] = rb1;
    }
    __syncthreads();
    cur ^= 1;
  }
  // epilogue: C-frag row = (lane>>4)*4 + r, col = lane&15
#pragma unroll
  for (int ni = 0; ni < 4; ++ni) {
    const int gc = col0 + wc * 64 + ni * 16 + l15;
    const float bv = (EPI & 1) ? bias[gc] : 0.f;
#pragma unroll
    for (int mi = 0; mi < 4; ++mi) {
#pragma unroll
      for (int r = 0; r < 4; ++r) {
        const int gr = row0 + wr * 64 + mi * 16 + g * 4 + r;
        if (gr >= M) continue;
        float v = acc[mi][ni][r] + bv;
        if (EPI & 2) v = fmaxf(v, 0.f);
        if (EPI & 4) v += res[(size_t)gr * N + gc];
        if (EPI & 8)  Cf[(size_t)gr * N + gc] = v;
        if (EPI & 16) Cb[(size_t)gr * N + gc] = (__bf16)v;
      }
    }
  }
}

// ---------------------------------------------------------------------
// Fused MFMA distance attention. grid (9 q-tiles of 128, B*NH).
// 4 waves; wave w owns q rows [w*32, w*32+32). Online softmax in
// C-fragment layout (row-reduce = shfl_xor over 16-lane groups).
// ---------------------------------------------------------------------
__global__ __launch_bounds__(256, 2) void attn_k(
    const __bf16* __restrict__ qkv, const float* __restrict__ sq2,
    const float* __restrict__ sk2, __bf16* __restrict__ O)
{
  __shared__ __bf16 Kl[64][104];   // row-major K tile, pad -> 2-way-free
  __shared__ __bf16 Vt[96][72];    // V transposed: Vt[hd][kv]
  __shared__ __bf16 Pl[128][72];   // P (bf16) staging for PV A-frags
  const int qt = blockIdx.x, bh = blockIdx.y;
  const int bb = bh >> 2, hh = bh & 3;
  const int tid = threadIdx.x;
  const int w = tid >> 6, lane = tid & 63;
  const int l15 = lane & 15, g = lane >> 4;
  const int q0 = qt * 128 + w * 32;
  const float* sq2h = sq2 + (size_t)bh * TSEQ;
  const float* sk2h = sk2 + (size_t)bh * TSEQ;

  bf16x8 qf[2][3];
  float sqv[2][4];
#pragma unroll
  for (int m = 0; m < 2; ++m) {
    int qr = q0 + m * 16 + l15; if (qr > TSEQ - 1) qr = TSEQ - 1;
    const __bf16* qp = qkv + (size_t)(bb * TSEQ + qr) * 1152 + hh * 96 + g * 8;
#pragma unroll
    for (int kf = 0; kf < 3; ++kf) qf[m][kf] = *(const bf16x8*)(qp + kf * 32);
#pragma unroll
    for (int r = 0; r < 4; ++r) {
      int qq = q0 + m * 16 + g * 4 + r; if (qq > TSEQ - 1) qq = TSEQ - 1;
      sqv[m][r] = sq2h[qq];
    }
  }

  float mrun[2][4], lrun[2][4];
  f32x4 accO[2][6];
#pragma unroll
  for (int m = 0; m < 2; ++m)
#pragma unroll
    for (int r = 0; r < 4; ++r) { mrun[m][r] = -INFINITY; lrun[m][r] = 0.f; }
#pragma unroll
  for (int m = 0; m < 2; ++m)
#pragma unroll
    for (int n = 0; n < 6; ++n) accO[m][n] = fzero4();

  for (int kt2 = 0; kt2 < 17; ++kt2) {
    const int kbase = kt2 * 64;
    // ---- stage K (row-major) and V (transposed) ----
    bf16x8 kr[3], vr[3];
#pragma unroll
    for (int i = 0; i < 3; ++i) {
      const int c = tid + i * 256;
      const int row = c / 12, cc = c - row * 12;
      const int kg = kbase + row;
      if (kg < TSEQ) {
        const __bf16* kp = qkv + (size_t)(bb * TSEQ + kg) * 1152 + 384 + hh * 96 + cc * 8;
        kr[i] = *(const bf16x8*)kp;
        vr[i] = *(const bf16x8*)(kp + 384);
      } else { kr[i] = bzero8(); vr[i] = bzero8(); }
    }
#pragma unroll
    for (int i = 0; i < 3; ++i) {
      const int c = tid + i * 256;
      const int row = c / 12, cc = c - row * 12;
      *(bf16x8*)&Kl[row][cc * 8] = kr[i];
#pragma unroll
      for (int j = 0; j < 8; ++j) Vt[cc * 8 + j][row] = vr[i][j];
    }
    __syncthreads();

    // ---- S = Q K^T (per wave: 2 M-frags x 4 k-col frags, K=96) ----
    f32x4 sf[2][4];
#pragma unroll
    for (int m = 0; m < 2; ++m)
#pragma unroll
      for (int ks = 0; ks < 4; ++ks) sf[m][ks] = fzero4();
#pragma unroll
    for (int ks = 0; ks < 4; ++ks) {
      bf16x8 kb0 = *(const bf16x8*)&Kl[ks * 16 + l15][g * 8];
      bf16x8 kb1 = *(const bf16x8*)&Kl[ks * 16 + l15][32 + g * 8];
      bf16x8 kb2 = *(const bf16x8*)&Kl[ks * 16 + l15][64 + g * 8];
#pragma unroll
      for (int m = 0; m < 2; ++m) {
        sf[m][ks] = __builtin_amdgcn_mfma_f32_16x16x32_bf16(qf[m][0], kb0, sf[m][ks], 0, 0, 0);
        sf[m][ks] = __builtin_amdgcn_mfma_f32_16x16x32_bf16(qf[m][1], kb1, sf[m][ks], 0, 0, 0);
        sf[m][ks] = __builtin_amdgcn_mfma_f32_16x16x32_bf16(qf[m][2], kb2, sf[m][ks], 0, 0, 0);
      }
    }

    // ---- distance scores + online softmax ----
    float nmax[2][4];
#pragma unroll
    for (int m = 0; m < 2; ++m)
#pragma unroll
      for (int r = 0; r < 4; ++r) nmax[m][r] = -INFINITY;
#pragma unroll
    for (int ks = 0; ks < 4; ++ks) {
      const int kgl = kbase + ks * 16 + l15;
      const bool kvld = (kgl < TSEQ);
      const float kv2 = kvld ? sk2h[kvld ? kgl : 0] : 0.f;
#pragma unroll
      for (int m = 0; m < 2; ++m)
#pragma unroll
        for (int r = 0; r < 4; ++r) {
          const float d2 = sqv[m][r] + kv2 - 2.f * sf[m][ks][r];
          const float s = kvld ? sqrtf(fmaxf(d2, 0.f)) * ATT_SCALE : -INFINITY;
          sf[m][ks][r] = s;
          nmax[m][r] = fmaxf(nmax[m][r], s);
        }
    }
#pragma unroll
    for (int m = 0; m < 2; ++m)
#pragma unroll
      for (int r = 0; r < 4; ++r) {
        float v = nmax[m][r];
        v = fmaxf(v, __shfl_xor(v, 1, 64));
        v = fmaxf(v, __shfl_xor(v, 2, 64));
        v = fmaxf(v, __shfl_xor(v, 4, 64));
        v = fmaxf(v, __shfl_xor(v, 8, 64));
        const float mn = fmaxf(mrun[m][r], v);
        const float f = __expf(mrun[m][r] - mn);
        mrun[m][r] = mn;
        lrun[m][r] *= f;
#pragma unroll
        for (int n = 0; n < 6; ++n) accO[m][n][r] *= f;
      }
    float ps[2][4] = {{0.f, 0.f, 0.f, 0.f}, {0.f, 0.f, 0.f, 0.f}};
#pragma unroll
    for (int ks = 0; ks < 4; ++ks)
#pragma unroll
      for (int m = 0; m < 2; ++m)
#pragma unroll
        for (int r = 0; r < 4; ++r) {
          const float p = __expf(sf[m][ks][r] - mrun[m][r]);
          ps[m][r] += p;
          Pl[w * 32 + m * 16 + g * 4 + r][ks * 16 + l15] = (__bf16)p;
        }
#pragma unroll
    for (int m = 0; m < 2; ++m)
#pragma unroll
      for (int r = 0; r < 4; ++r) {
        float v = ps[m][r];
        v += __shfl_xor(v, 1, 64);
        v += __shfl_xor(v, 2, 64);
        v += __shfl_xor(v, 4, 64);
        v += __shfl_xor(v, 8, 64);
        lrun[m][r] += v;
      }

    // ---- O += P V ----
#pragma unroll
    for (int ks2 = 0; ks2 < 2; ++ks2) {
      bf16x8 pa[2];
#pragma unroll
      for (int m = 0; m < 2; ++m)
        pa[m] = *(const bf16x8*)&Pl[w * 32 + m * 16 + l15][ks2 * 32 + g * 8];
#pragma unroll
      for (int n = 0; n < 6; ++n) {
        bf16x8 vb = *(const bf16x8*)&Vt[n * 16 + l15][ks2 * 32 + g * 8];
#pragma unroll
        for (int m = 0; m < 2; ++m)
          accO[m][n] = __builtin_amdgcn_mfma_f32_16x16x32_bf16(pa[m], vb, accO[m][n], 0, 0, 0);
      }
    }
    __syncthreads();
  }

  // ---- normalize + store bf16 ----
#pragma unroll
  for (int m = 0; m < 2; ++m)
#pragma unroll
    for (int r = 0; r < 4; ++r) {
      const int qr = q0 + m * 16 + g * 4 + r;
      if (qr >= TSEQ) continue;
      const float inv = 1.f / lrun[m][r];
#pragma unroll
      for (int n = 0; n < 6; ++n)
        O[(size_t)(bb * TSEQ + qr) * 384 + hh * 96 + n * 16 + l15] =
            (__bf16)(accO[m][n][r] * inv);
    }
}

// ---------------------------------------------------------------------
// im2col + fp32->bf16: Ai[16384][768]
// ---------------------------------------------------------------------
__global__ __launch_bounds__(256) void im2col_k(
    const float* __restrict__ x, __bf16* __restrict__ Ai)
{
  const int i = blockIdx.x * 256 + threadIdx.x;   // 8-elem chunks
  const int row = i / 96;
  const int k = (i - row * 96) * 8;
  const int b = row >> 10;
  const int pidx = row & 1023;
  const int py = pidx >> 5, px = pidx & 31;
  const int cc = k >> 8;
  const int rem = k & 255;
  const int p = rem >> 4, q = rem & 15;
  const float* src = x + ((size_t)((b * 3 + cc) * IMGSZ + py * 16 + p)) * IMGSZ
                       + px * 16 + q;
  const float4 a = *(const float4*)src;
  const float4 c4 = *(const float4*)(src + 4);
  bf16x8 o;
  o[0] = (__bf16)a.x;  o[1] = (__bf16)a.y;  o[2] = (__bf16)a.z;  o[3] = (__bf16)a.w;
  o[4] = (__bf16)c4.x; o[5] = (__bf16)c4.y; o[6] = (__bf16)c4.z; o[7] = (__bf16)c4.w;
  *(bf16x8*)&Ai[(size_t)i * 8] = o;
}

// ---------------------------------------------------------------------
// weight transpose + convert: dst[N][K] bf16 = src[K][N] fp32, per z
// ---------------------------------------------------------------------
__global__ void wt_k(const float* __restrict__ src, size_t srcZ,
                     __bf16* __restrict__ dst, size_t dstZ, int K, int N)
{
  __shared__ float t[32][33];
  const float* s = src + blockIdx.z * srcZ;
  __bf16* d = dst + blockIdx.z * dstZ;
  const int k0 = blockIdx.x * 32, n0 = blockIdx.y * 32;
  const int tx = threadIdx.x, ty = threadIdx.y;   // 32 x 8
#pragma unroll
  for (int i = 0; i < 4; ++i)
    t[ty + 8 * i][tx] = s[(size_t)(k0 + ty + 8 * i) * N + n0 + tx];
  __syncthreads();
#pragma unroll
  for (int i = 0; i < 4; ++i)
    d[(size_t)(n0 + ty + 8 * i) * K + k0 + tx] = (__bf16)t[tx][ty + 8 * i];
}

// plain fp32 -> bf16 convert (conv_w already [N][K])
__global__ void cvt_k(const float* __restrict__ src, __bf16* __restrict__ dst, int n8)
{
  const int i = blockIdx.x * 256 + threadIdx.x;
  if (i >= n8) return;
  const float4 a = *(const float4*)&src[(size_t)i * 8];
  const float4 b = *(const float4*)&src[(size_t)i * 8 + 4];
  bf16x8 o;
  o[0] = (__bf16)a.x; o[1] = (__bf16)a.y; o[2] = (__bf16)a.z; o[3] = (__bf16)a.w;
  o[4] = (__bf16)b.x; o[5] = (__bf16)b.y; o[6] = (__bf16)b.z; o[7] = (__bf16)b.w;
  *(bf16x8*)&dst[(size_t)i * 8] = o;
}

// ---------------------------------------------------------------------
// h[b,t,:] = (t==0 ? cls : pe[b,t-1]) + pos[t]   (fp32)
// ---------------------------------------------------------------------
__global__ __launch_bounds__(256) void embed_k(
    const float* __restrict__ pe, const float* __restrict__ cls,
    const float* __restrict__ pos, float* __restrict__ h)
{
  const int i = blockIdx.x * 256 + threadIdx.x;   // float4 chunks
  const int row = i / 96;
  const int d4 = (i - row * 96) * 4;
  const int b = row / TSEQ;
  const int t = row - b * TSEQ;
  const float4 po = *(const float4*)&pos[(size_t)t * DMODEL + d4];
  float4 r;
  if (t == 0) {
    const float4 cv = *(const float4*)&cls[d4];
    r = make_float4(cv.x + po.x, cv.y + po.y, cv.z + po.z, cv.w + po.w);
  } else {
    const float4 pv = *(const float4*)&pe[((size_t)(b * NPATCHI + t - 1)) * DMODEL + d4];
    r = make_float4(pv.x + po.x, pv.y + po.y, pv.z + po.z, pv.w + po.w);
  }
  *(float4*)&h[(size_t)row * DMODEL + d4] = r;
}

// ---------------------------------------------------------------------
// LayerNorm fp32 -> bf16 out
// ---------------------------------------------------------------------
__global__ __launch_bounds__(256) void ln_k(
    const float* __restrict__ in, const float* __restrict__ sc,
    const float* __restrict__ bi, __bf16* __restrict__ out)
{
  const int w = threadIdx.x >> 6, lane = threadIdx.x & 63;
  const int row = blockIdx.x * 4 + w;
  const float* r = in + (size_t)row * DMODEL;
  float v[6], sum = 0.f, ss = 0.f;
#pragma unroll
  for (int j = 0; j < 6; ++j) {
    const float xv = r[lane + 64 * j];
    v[j] = xv; sum += xv; ss += xv * xv;
  }
#pragma unroll
  for (int m = 1; m < 64; m <<= 1) {
    sum += __shfl_xor(sum, m, 64);
    ss  += __shfl_xor(ss,  m, 64);
  }
  const float mean = sum * (1.f / 384.f);
  const float var  = ss * (1.f / 384.f) - mean * mean;
  const float rstd = rsqrtf(var + 1e-5f);
  __bf16* o = out + (size_t)row * DMODEL;
#pragma unroll
  for (int j = 0; j < 6; ++j) {
    const int col = lane + 64 * j;
    o[col] = (__bf16)((v[j] - mean) * rstd * sc[col] + bi[col]);
  }
}

// ---------------------------------------------------------------------
// per-(b,h,t) |q|^2 and |k|^2 from bf16 qkv
// ---------------------------------------------------------------------
__global__ __launch_bounds__(256) void sumsq_k(
    const __bf16* __restrict__ qkv, float* __restrict__ sq2,
    float* __restrict__ sk2)
{
  const int w = threadIdx.x >> 6, lane = threadIdx.x & 63;
  const int row = blockIdx.x * 4 + w;
  const int h = lane >> 4, lg = lane & 15;
  const __bf16* q = qkv + (size_t)row * 1152 + h * HDIM;
  float s1 = 0.f, s2 = 0.f;
#pragma unroll
  for (int j = 0; j < 6; ++j) {
    const float a = (float)q[lg + 16 * j];
    const float c = (float)q[384 + lg + 16 * j];
    s1 += a * a; s2 += c * c;
  }
#pragma unroll
  for (int m = 1; m < 16; m <<= 1) {
    s1 += __shfl_xor(s1, m, 64);
    s2 += __shfl_xor(s2, m, 64);
  }
  if (lg == 0) {
    const int b = row / TSEQ, t = row - b * TSEQ;
    sq2[((size_t)b * NHEAD + h) * TSEQ + t] = s1;
    sk2[((size_t)b * NHEAD + h) * TSEQ + t] = s2;
  }
}

// ---------------------------------------------------------------------
// head: final LN (cls rows) + proj + log_softmax + NLL
// ---------------------------------------------------------------------
__global__ __launch_bounds__(256) void head_k(
    const float* __restrict__ h, const float* __restrict__ gs,
    const float* __restrict__ gb, const float* __restrict__ pw,
    const float* __restrict__ pb, const int* __restrict__ tgt,
    float* __restrict__ out)
{
  __shared__ float lg[BATCH][2];
  const int w = threadIdx.x >> 6, lane = threadIdx.x & 63;
  for (int b = w; b < BATCH; b += 4) {
    const float* r = h + (size_t)b * TSEQ * DMODEL;
    float v[6], sum = 0.f, ss = 0.f;
#pragma unroll
    for (int j = 0; j < 6; ++j) {
      const float xv = r[lane + 64 * j];
      v[j] = xv; sum += xv; ss += xv * xv;
    }
#pragma unroll
    for (int m = 1; m < 64; m <<= 1) {
      sum += __shfl_xor(sum, m, 64);
      ss  += __shfl_xor(ss,  m, 64);
    }
    const float mean = sum * (1.f / 384.f);
    const float var  = ss * (1.f / 384.f) - mean * mean;
    const float rstd = rsqrtf(var + 1e-5f);
    float l0 = 0.f, l1 = 0.f;
#pragma unroll
    for (int j = 0; j < 6; ++j) {
      const int col = lane + 64 * j;
      const float hnv = (v[j] - mean) * rstd * gs[col] + gb[col];
      l0 = fmaf(hnv, pw[col * 2 + 0], l0);
      l1 = fmaf(hnv, pw[col * 2 + 1], l1);
    }
#pragma unroll
    for (int m = 1; m < 64; m <<= 1) {
      l0 += __shfl_xor(l0, m, 64);
      l1 += __shfl_xor(l1, m, 64);
    }
    if (lane == 0) { lg[b][0] = l0 + pb[0]; lg[b][1] = l1 + pb[1]; }
  }
  __syncthreads();
  if (threadIdx.x < 32)
    out[threadIdx.x] = lg[threadIdx.x >> 1][threadIdx.x & 1];
  if (threadIdx.x == 0) {
    float acc = 0.f;
    for (int b = 0; b < BATCH; ++b) {
      const float a = lg[b][0], c = lg[b][1];
      const float mx = fmaxf(a, c);
      const float lse = mx + logf(expf(a - mx) + expf(c - mx));
      const float lp = ((tgt[b] == 0) ? a : c) - lse;
      acc += lp;
    }
    out[32] = -acc * (1.f / BATCH);
  }
}

// ---------------------------------------------------------------------
extern "C" void kernel_launch(void* const* d_in, const int* in_sizes, int n_in,
                              void* d_out, int out_size, void* d_ws, size_t ws_size,
                              hipStream_t stream)
{
  const float* x       = (const float*)d_in[0];
  const int*   targets = (const int*)  d_in[1];
  const float* conv_w  = (const float*)d_in[2];
  const float* conv_b  = (const float*)d_in[3];
  const float* cls_tok = (const float*)d_in[4];
  const float* pos_emb = (const float*)d_in[5];
  const float* ln1_s   = (const float*)d_in[6];
  const float* ln1_b   = (const float*)d_in[7];
  const float* ln2_s   = (const float*)d_in[8];
  const float* ln2_b   = (const float*)d_in[9];
  const float* wq      = (const float*)d_in[10];
  const float* wk      = (const float*)d_in[11];
  const float* wv      = (const float*)d_in[12];
  const float* wo      = (const float*)d_in[13];
  const float* bo      = (const float*)d_in[14];
  const float* w1      = (const float*)d_in[15];
  const float* b1      = (const float*)d_in[16];
  const float* w2      = (const float*)d_in[17];
  const float* b2      = (const float*)d_in[18];
  const float* lnf_s   = (const float*)d_in[19];
  const float* lnf_b   = (const float*)d_in[20];
  const float* proj_w  = (const float*)d_in[21];
  const float* proj_b  = (const float*)d_in[22];

  char* p = (char*)d_ws;
  auto alloc = [&](size_t bytes) -> void* {
    void* r = (void*)p; p += (bytes + 255) & ~(size_t)255; return r;
  };
  float*  h     = (float*) alloc((size_t)MROWS * DMODEL * 4);        // 25.19 MB
  __bf16* hn    = (__bf16*)alloc((size_t)MROWS * DMODEL * 2);        // 12.60 MB
  __bf16* qkv   = (__bf16*)alloc((size_t)MROWS * 1152 * 2);          // 37.79 MB
  __bf16* Obuf  = (__bf16*)alloc((size_t)MROWS * DMODEL * 2);        // 12.60 MB (adjacent to qkv)
  float*  pe    = (float*) alloc((size_t)MPATCH * DMODEL * 4);       // 25.17 MB
  float*  sq2   = (float*) alloc((size_t)BATCH * NHEAD * TSEQ * 4);
  float*  sk2   = (float*) alloc((size_t)BATCH * NHEAD * TSEQ * 4);
  __bf16* cwb   = (__bf16*)alloc((size_t)DMODEL * KPE * 2);
  __bf16* wqkvT = (__bf16*)alloc((size_t)NBLK * 1152 * DMODEL * 2);
  __bf16* woT   = (__bf16*)alloc((size_t)NBLK * DMODEL * DMODEL * 2);
  __bf16* w1T   = (__bf16*)alloc((size_t)NBLK * FFDIM * DMODEL * 2);
  __bf16* w2T   = (__bf16*)alloc((size_t)NBLK * DMODEL * FFDIM * 2);
  if ((size_t)(p - (char*)d_ws) > ws_size) return;
  __bf16* Ai  = qkv;   // im2col buffer (25.2 MB <= 37.8 MB), dead before QKV
  __bf16* ffb = qkv;   // MLP hidden [16400][1536] spans qkv+Obuf exactly

  // ---- weight conversion ----
  cvt_k<<<144, 256, 0, stream>>>(conv_w, cwb, (DMODEL * KPE) / 8);
  {
    dim3 blk(32, 8);
    // qkv: dst rows [0,384)=wq, [384,768)=wk, [768,1152)=wv per block z
    wt_k<<<dim3(12, 12, 3), blk, 0, stream>>>(wq, (size_t)DMODEL * DMODEL,
        wqkvT + 0,               (size_t)1152 * DMODEL, DMODEL, DMODEL);
    wt_k<<<dim3(12, 12, 3), blk, 0, stream>>>(wk, (size_t)DMODEL * DMODEL,
        wqkvT + 384 * DMODEL,    (size_t)1152 * DMODEL, DMODEL, DMODEL);
    wt_k<<<dim3(12, 12, 3), blk, 0, stream>>>(wv, (size_t)DMODEL * DMODEL,
        wqkvT + 768 * DMODEL,    (size_t)1152 * DMODEL, DMODEL, DMODEL);
    wt_k<<<dim3(12, 12, 3), blk, 0, stream>>>(wo, (size_t)DMODEL * DMODEL,
        woT, (size_t)DMODEL * DMODEL, DMODEL, DMODEL);
    wt_k<<<dim3(12, 48, 3), blk, 0, stream>>>(w1, (size_t)DMODEL * FFDIM,
        w1T, (size_t)FFDIM * DMODEL, DMODEL, FFDIM);
    wt_k<<<dim3(48, 12, 3), blk, 0, stream>>>(w2, (size_t)FFDIM * DMODEL,
        w2T, (size_t)DMODEL * FFDIM, FFDIM, DMODEL);
  }

  // ---- patch embedding ----
  im2col_k<<<6144, 256, 0, stream>>>(x, Ai);
  mgemm_k<9><<<dim3(128, 3), 256, 0, stream>>>(   // bias | f32 out
      Ai, cwb, conv_b, nullptr, pe, nullptr, MPATCH, DMODEL, KPE);
  embed_k<<<6150, 256, 0, stream>>>(pe, cls_tok, pos_emb, h);

  // ---- transformer blocks ----
  for (int i = 0; i < NBLK; ++i) {
    ln_k<<<4100, 256, 0, stream>>>(h, ln1_s + i * DMODEL, ln1_b + i * DMODEL, hn);
    mgemm_k<16><<<dim3(129, 9), 256, 0, stream>>>(  // bf16 out
        hn, wqkvT + (size_t)i * 1152 * DMODEL, nullptr, nullptr,
        nullptr, qkv, MROWS, 1152, DMODEL);
    sumsq_k<<<4100, 256, 0, stream>>>(qkv, sq2, sk2);
    attn_k<<<dim3(9, BATCH * NHEAD), 256, 0, stream>>>(qkv, sq2, sk2, Obuf);
    mgemm_k<13><<<dim3(129, 3), 256, 0, stream>>>(  // bias | res | f32 out
        Obuf, woT + (size_t)i * DMODEL * DMODEL, bo + i * DMODEL, h,
        h, nullptr, MROWS, DMODEL, DMODEL);
    ln_k<<<4100, 256, 0, stream>>>(h, ln2_s + i * DMODEL, ln2_b + i * DMODEL, hn);
    mgemm_k<19><<<dim3(129, 12), 256, 0, stream>>>( // bias | relu | bf16 out
        hn, w1T + (size_t)i * FFDIM * DMODEL, b1 + i * FFDIM, nullptr,
        nullptr, ffb, MROWS, FFDIM, DMODEL);
    mgemm_k<13><<<dim3(129, 3), 256, 0, stream>>>(  // bias | res | f32 out
        ffb, w2T + (size_t)i * DMODEL * FFDIM, b2 + i * DMODEL, h,
        h, nullptr, MROWS, DMODEL, FFDIM);
  }

  // ---- head ----
  head_k<<<1, 256, 0, stream>>>(h, lnf_s, lnf_b, proj_w, proj_b, targets,
                                (float*)d_out);
}

// Round 3
// 1296.279 us; speedup vs baseline: 3.6851x; 1.0418x over previous
//
#include <hip/hip_runtime.h>
#include <math.h>

// =====================================================================
// ViT discriminator forward — round 3.
// Changes vs round 2 (attention only):
//  * V transposed ONCE per layer to Vt[bh][96][1088] (vtr_k) — kills the
//    12-way bank-conflict per-element scatter in attn staging.
//  * attn: 64-row q-tiles (grid 17x64=1088 blocks), LDS 36KB -> 4 blk/CU.
//  * async-stage split: chunk c+1 global loads issued before compute(c).
//  * bank-audited LDS strides (104 / 72 elems); setprio around MFMA.
// =====================================================================

#define BATCH   16
#define TSEQ    1025
#define DMODEL  384
#define NHEAD   4
#define HDIM    96
#define NBLK    3
#define FFDIM   1536
#define IMGSZ   512
#define NPATCHI 1024
#define MROWS   (BATCH*TSEQ)      // 16400
#define MPATCH  (BATCH*NPATCHI)   // 16384
#define KPE     768
#define VTS     1088              // padded t-stride of Vt (17*64)
#define ATT_SCALE 0.10206207261596577f  // 1/sqrt(96)

typedef __attribute__((ext_vector_type(8))) __bf16 bf16x8;
typedef __attribute__((ext_vector_type(4))) float  f32x4;

__device__ __forceinline__ f32x4 fzero4() {
  f32x4 v; v[0] = 0.f; v[1] = 0.f; v[2] = 0.f; v[3] = 0.f; return v;
}
__device__ __forceinline__ bf16x8 bzero8() {
  bf16x8 v;
#pragma unroll
  for (int j = 0; j < 8; ++j) v[j] = (__bf16)0.f;
  return v;
}

// ---------------------------------------------------------------------
// bf16 MFMA GEMM: C[M,N] = A[M,K] @ Bt[N,K]^T  (unchanged from round 2)
// EPI bits: 1=+bias, 2=relu, 4=+res(fp32), 8=write Cf(fp32), 16=write Cb(bf16)
// ---------------------------------------------------------------------
template<int EPI>
__global__ __launch_bounds__(256, 2) void mgemm_k(
    const __bf16* __restrict__ A, const __bf16* __restrict__ Bt,
    const float* __restrict__ bias, const float* __restrict__ res,
    float* __restrict__ Cf, __bf16* __restrict__ Cb, int M, int N, int K)
{
  __shared__ __bf16 Al[2][128][40];
  __shared__ __bf16 Bl[2][128][40];
  const int tid = threadIdx.x;
  const int lane = tid & 63;
  const int w = tid >> 6;
  const int wr = w >> 1, wc = w & 1;
  const int l15 = lane & 15, g = lane >> 4;
  const int row0 = blockIdx.x * 128, col0 = blockIdx.y * 128;
  const int srow = tid >> 1, soff = (tid & 1) * 16;
  int ar = row0 + srow; if (ar > M - 1) ar = M - 1;
  const __bf16* ap = A + (size_t)ar * K + soff;
  const __bf16* bp = Bt + (size_t)(col0 + srow) * K + soff;

  f32x4 acc[4][4];
#pragma unroll
  for (int i = 0; i < 4; ++i)
#pragma unroll
    for (int j = 0; j < 4; ++j) acc[i][j] = fzero4();

  const int nk = K >> 5;
  bf16x8 ra0 = *(const bf16x8*)ap;
  bf16x8 ra1 = *(const bf16x8*)(ap + 8);
  bf16x8 rb0 = *(const bf16x8*)bp;
  bf16x8 rb1 = *(const bf16x8*)(bp + 8);
  *(bf16x8*)&Al[0][srow][soff]     = ra0;
  *(bf16x8*)&Al[0][srow][soff + 8] = ra1;
  *(bf16x8*)&Bl[0][srow][soff]     = rb0;
  *(bf16x8*)&Bl[0][srow][soff + 8] = rb1;
  __syncthreads();
  int cur = 0;
  for (int kt = 0; kt < nk; ++kt) {
    const bool pf = (kt + 1 < nk);
    if (pf) {
      const __bf16* a2 = ap + (size_t)(kt + 1) * 32;
      const __bf16* b2 = bp + (size_t)(kt + 1) * 32;
      ra0 = *(const bf16x8*)a2; ra1 = *(const bf16x8*)(a2 + 8);
      rb0 = *(const bf16x8*)b2; rb1 = *(const bf16x8*)(b2 + 8);
    }
    bf16x8 af[4], bfr[4];
#pragma unroll
    for (int mi = 0; mi < 4; ++mi)
      af[mi] = *(const bf16x8*)&Al[cur][wr * 64 + mi * 16 + l15][g * 8];
#pragma unroll
    for (int ni = 0; ni < 4; ++ni)
      bfr[ni] = *(const bf16x8*)&Bl[cur][wc * 64 + ni * 16 + l15][g * 8];
#pragma unroll
    for (int mi = 0; mi < 4; ++mi)
#pragma unroll
      for (int ni = 0; ni < 4; ++ni)
        acc[mi][ni] = __builtin_amdgcn_mfma_f32_16x16x32_bf16(
            af[mi], bfr[ni], acc[mi][ni], 0, 0, 0);
    if (pf) {
      *(bf16x8*)&Al[cur ^ 1][srow][soff]     = ra0;
      *(bf16x8*)&Al[cur ^ 1][srow][soff + 8] = ra1;
      *(bf16x8*)&Bl[cur ^ 1][srow][soff]     = rb0;
      *(bf16x8*)&Bl[cur ^ 1][srow][soff + 8] = rb1;
    }
    __syncthreads();
    cur ^= 1;
  }
#pragma unroll
  for (int ni = 0; ni < 4; ++ni) {
    const int gc = col0 + wc * 64 + ni * 16 + l15;
    const float bv = (EPI & 1) ? bias[gc] : 0.f;
#pragma unroll
    for (int mi = 0; mi < 4; ++mi) {
#pragma unroll
      for (int r = 0; r < 4; ++r) {
        const int gr = row0 + wr * 64 + mi * 16 + g * 4 + r;
        if (gr >= M) continue;
        float v = acc[mi][ni][r] + bv;
        if (EPI & 2) v = fmaxf(v, 0.f);
        if (EPI & 4) v += res[(size_t)gr * N + gc];
        if (EPI & 8)  Cf[(size_t)gr * N + gc] = v;
        if (EPI & 16) Cb[(size_t)gr * N + gc] = (__bf16)v;
      }
    }
  }
}

// ---------------------------------------------------------------------
// V transpose: Vt[bh][96][VTS] <- qkv[.,768+h*96+.]; zero-fill t>=TSEQ
// ---------------------------------------------------------------------
__global__ void vtr_k(const __bf16* __restrict__ qkv, __bf16* __restrict__ Vt)
{
  __shared__ __bf16 t[32][33];
  const int bh = blockIdx.z;
  const int bb = bh >> 2, hh = bh & 3;
  const int t0 = blockIdx.x * 32;
  const int d0 = blockIdx.y * 32;
  const int tx = threadIdx.x, ty = threadIdx.y;  // 32 x 8
#pragma unroll
  for (int i = 0; i < 4; ++i) {
    const int tt = t0 + ty + 8 * i;
    t[ty + 8 * i][tx] = (tt < TSEQ)
        ? qkv[(size_t)(bb * TSEQ + tt) * 1152 + 768 + hh * 96 + d0 + tx]
        : (__bf16)0.f;
  }
  __syncthreads();
#pragma unroll
  for (int i = 0; i < 4; ++i)
    Vt[((size_t)bh * 96 + d0 + ty + 8 * i) * VTS + t0 + tx] = t[tx][ty + 8 * i];
}

// ---------------------------------------------------------------------
// Fused MFMA distance attention, round 3.
// grid (17, 64). 4 waves; wave w owns q rows [qt*64+w*16, +16).
// Single-buffer LDS + register prefetch of next chunk (async-stage).
// ---------------------------------------------------------------------
__global__ __launch_bounds__(256, 4) void attn_k(
    const __bf16* __restrict__ qkv, const __bf16* __restrict__ Vtg,
    const float* __restrict__ sq2, const float* __restrict__ sk2,
    __bf16* __restrict__ O)
{
  __shared__ __bf16 Kl[64][104];  // stride 208B: b128 reads 8 lanes/quad
  __shared__ __bf16 Vl[96][72];   // stride 144B: 4(l15+g) quad spread
  __shared__ __bf16 Pl[64][72];   // wave-private rows
  const int qt = blockIdx.x, bh = blockIdx.y;
  const int bb = bh >> 2, hh = bh & 3;
  const int tid = threadIdx.x;
  const int w = tid >> 6, lane = tid & 63;
  const int l15 = lane & 15, g = lane >> 4;
  const int q0 = qt * 64 + w * 16;
  const float* sq2h = sq2 + (size_t)bh * TSEQ;
  const float* sk2h = sk2 + (size_t)bh * TSEQ;
  const __bf16* vbase = Vtg + (size_t)bh * 96 * VTS;

  // ---- Q fragments + per-row |q|^2 ----
  bf16x8 qf[3];
  float sqv[4];
  {
    int qr = q0 + l15; if (qr > TSEQ - 1) qr = TSEQ - 1;
    const __bf16* qp = qkv + (size_t)(bb * TSEQ + qr) * 1152 + hh * 96 + g * 8;
#pragma unroll
    for (int kf = 0; kf < 3; ++kf) qf[kf] = *(const bf16x8*)(qp + kf * 32);
#pragma unroll
    for (int r = 0; r < 4; ++r) {
      int qq = q0 + g * 4 + r; if (qq > TSEQ - 1) qq = TSEQ - 1;
      sqv[r] = sq2h[qq];
    }
  }

  float mrun[4], lrun[4];
  f32x4 accO[6];
#pragma unroll
  for (int r = 0; r < 4; ++r) { mrun[r] = -INFINITY; lrun[r] = 0.f; }
#pragma unroll
  for (int n = 0; n < 6; ++n) accO[n] = fzero4();

  bf16x8 kr[3], vr[3];
  auto load_chunk = [&](int c) {
    const int kbase = c * 64;
#pragma unroll
    for (int i = 0; i < 3; ++i) {
      const int idx = tid + i * 256;            // 0..767
      const int row = idx / 12, cc = idx - row * 12;  // K: 64 x 12
      const int kg = kbase + row;
      kr[i] = (kg < TSEQ)
          ? *(const bf16x8*)(qkv + (size_t)(bb * TSEQ + kg) * 1152 + 384
                             + hh * 96 + cc * 8)
          : bzero8();
      const int d = idx >> 3, o8 = (idx & 7) * 8;     // V: 96 x 8
      vr[i] = *(const bf16x8*)(vbase + (size_t)d * VTS + kbase + o8);
    }
  };

  load_chunk(0);

  for (int c = 0; c < 17; ++c) {
    const int kbase = c * 64;
    __syncthreads();             // all waves done reading previous chunk
#pragma unroll
    for (int i = 0; i < 3; ++i) {
      const int idx = tid + i * 256;
      const int row = idx / 12, cc = idx - row * 12;
      *(bf16x8*)&Kl[row][cc * 8] = kr[i];
      const int d = idx >> 3, o8 = (idx & 7) * 8;
      *(bf16x8*)&Vl[d][o8] = vr[i];
    }
    __syncthreads();             // LDS published
    if (c + 1 < 17) load_chunk(c + 1);  // overlap HBM latency with compute

    // ---- S = Q K^T ----
    f32x4 sf[4];
#pragma unroll
    for (int ks = 0; ks < 4; ++ks) sf[ks] = fzero4();
    __builtin_amdgcn_s_setprio(1);
#pragma unroll
    for (int ks = 0; ks < 4; ++ks) {
      bf16x8 kb0 = *(const bf16x8*)&Kl[ks * 16 + l15][g * 8];
      bf16x8 kb1 = *(const bf16x8*)&Kl[ks * 16 + l15][32 + g * 8];
      bf16x8 kb2 = *(const bf16x8*)&Kl[ks * 16 + l15][64 + g * 8];
      sf[ks] = __builtin_amdgcn_mfma_f32_16x16x32_bf16(qf[0], kb0, sf[ks], 0, 0, 0);
      sf[ks] = __builtin_amdgcn_mfma_f32_16x16x32_bf16(qf[1], kb1, sf[ks], 0, 0, 0);
      sf[ks] = __builtin_amdgcn_mfma_f32_16x16x32_bf16(qf[2], kb2, sf[ks], 0, 0, 0);
    }
    __builtin_amdgcn_s_setprio(0);

    // ---- distance scores + online softmax ----
    float nmax[4] = {-INFINITY, -INFINITY, -INFINITY, -INFINITY};
#pragma unroll
    for (int ks = 0; ks < 4; ++ks) {
      const int kgl = kbase + ks * 16 + l15;
      const bool kvld = (kgl < TSEQ);
      const float kv2 = sk2h[kvld ? kgl : 0];
#pragma unroll
      for (int r = 0; r < 4; ++r) {
        const float d2 = sqv[r] + kv2 - 2.f * sf[ks][r];
        const float s = kvld ? sqrtf(fmaxf(d2, 0.f)) * ATT_SCALE : -INFINITY;
        sf[ks][r] = s;
        nmax[r] = fmaxf(nmax[r], s);
      }
    }
#pragma unroll
    for (int r = 0; r < 4; ++r) {
      float v = nmax[r];
      v = fmaxf(v, __shfl_xor(v, 1, 64));
      v = fmaxf(v, __shfl_xor(v, 2, 64));
      v = fmaxf(v, __shfl_xor(v, 4, 64));
      v = fmaxf(v, __shfl_xor(v, 8, 64));
      const float mn = fmaxf(mrun[r], v);
      const float f = __expf(mrun[r] - mn);
      mrun[r] = mn;
      lrun[r] *= f;
#pragma unroll
      for (int n = 0; n < 6; ++n) accO[n][r] *= f;
    }
    float ps[4] = {0.f, 0.f, 0.f, 0.f};
#pragma unroll
    for (int ks = 0; ks < 4; ++ks)
#pragma unroll
      for (int r = 0; r < 4; ++r) {
        const float p = __expf(sf[ks][r] - mrun[r]);
        ps[r] += p;
        Pl[w * 16 + g * 4 + r][ks * 16 + l15] = (__bf16)p;
      }
#pragma unroll
    for (int r = 0; r < 4; ++r) {
      float v = ps[r];
      v += __shfl_xor(v, 1, 64);
      v += __shfl_xor(v, 2, 64);
      v += __shfl_xor(v, 4, 64);
      v += __shfl_xor(v, 8, 64);
      lrun[r] += v;
    }

    // ---- O += P V ----
    __builtin_amdgcn_s_setprio(1);
#pragma unroll
    for (int ks2 = 0; ks2 < 2; ++ks2) {
      bf16x8 pa = *(const bf16x8*)&Pl[w * 16 + l15][ks2 * 32 + g * 8];
#pragma unroll
      for (int n = 0; n < 6; ++n) {
        bf16x8 vb = *(const bf16x8*)&Vl[n * 16 + l15][ks2 * 32 + g * 8];
        accO[n] = __builtin_amdgcn_mfma_f32_16x16x32_bf16(pa, vb, accO[n], 0, 0, 0);
      }
    }
    __builtin_amdgcn_s_setprio(0);
  }

  // ---- normalize + store ----
#pragma unroll
  for (int r = 0; r < 4; ++r) {
    const int qr = q0 + g * 4 + r;
    if (qr >= TSEQ) continue;
    const float inv = 1.f / lrun[r];
#pragma unroll
    for (int n = 0; n < 6; ++n)
      O[(size_t)(bb * TSEQ + qr) * 384 + hh * 96 + n * 16 + l15] =
          (__bf16)(accO[n][r] * inv);
  }
}

// ---------------------------------------------------------------------
// im2col + fp32->bf16: Ai[16384][768]
// ---------------------------------------------------------------------
__global__ __launch_bounds__(256) void im2col_k(
    const float* __restrict__ x, __bf16* __restrict__ Ai)
{
  const int i = blockIdx.x * 256 + threadIdx.x;
  const int row = i / 96;
  const int k = (i - row * 96) * 8;
  const int b = row >> 10;
  const int pidx = row & 1023;
  const int py = pidx >> 5, px = pidx & 31;
  const int cc = k >> 8;
  const int rem = k & 255;
  const int p = rem >> 4, q = rem & 15;
  const float* src = x + ((size_t)((b * 3 + cc) * IMGSZ + py * 16 + p)) * IMGSZ
                       + px * 16 + q;
  const float4 a = *(const float4*)src;
  const float4 c4 = *(const float4*)(src + 4);
  bf16x8 o;
  o[0] = (__bf16)a.x;  o[1] = (__bf16)a.y;  o[2] = (__bf16)a.z;  o[3] = (__bf16)a.w;
  o[4] = (__bf16)c4.x; o[5] = (__bf16)c4.y; o[6] = (__bf16)c4.z; o[7] = (__bf16)c4.w;
  *(bf16x8*)&Ai[(size_t)i * 8] = o;
}

// ---------------------------------------------------------------------
// weight transpose + convert: dst[N][K] bf16 = src[K][N] fp32, per z
// ---------------------------------------------------------------------
__global__ void wt_k(const float* __restrict__ src, size_t srcZ,
                     __bf16* __restrict__ dst, size_t dstZ, int K, int N)
{
  __shared__ float t[32][33];
  const float* s = src + blockIdx.z * srcZ;
  __bf16* d = dst + blockIdx.z * dstZ;
  const int k0 = blockIdx.x * 32, n0 = blockIdx.y * 32;
  const int tx = threadIdx.x, ty = threadIdx.y;
#pragma unroll
  for (int i = 0; i < 4; ++i)
    t[ty + 8 * i][tx] = s[(size_t)(k0 + ty + 8 * i) * N + n0 + tx];
  __syncthreads();
#pragma unroll
  for (int i = 0; i < 4; ++i)
    d[(size_t)(n0 + ty + 8 * i) * K + k0 + tx] = (__bf16)t[tx][ty + 8 * i];
}

__global__ void cvt_k(const float* __restrict__ src, __bf16* __restrict__ dst, int n8)
{
  const int i = blockIdx.x * 256 + threadIdx.x;
  if (i >= n8) return;
  const float4 a = *(const float4*)&src[(size_t)i * 8];
  const float4 b = *(const float4*)&src[(size_t)i * 8 + 4];
  bf16x8 o;
  o[0] = (__bf16)a.x; o[1] = (__bf16)a.y; o[2] = (__bf16)a.z; o[3] = (__bf16)a.w;
  o[4] = (__bf16)b.x; o[5] = (__bf16)b.y; o[6] = (__bf16)b.z; o[7] = (__bf16)b.w;
  *(bf16x8*)&dst[(size_t)i * 8] = o;
}

// ---------------------------------------------------------------------
__global__ __launch_bounds__(256) void embed_k(
    const float* __restrict__ pe, const float* __restrict__ cls,
    const float* __restrict__ pos, float* __restrict__ h)
{
  const int i = blockIdx.x * 256 + threadIdx.x;
  const int row = i / 96;
  const int d4 = (i - row * 96) * 4;
  const int b = row / TSEQ;
  const int t = row - b * TSEQ;
  const float4 po = *(const float4*)&pos[(size_t)t * DMODEL + d4];
  float4 r;
  if (t == 0) {
    const float4 cv = *(const float4*)&cls[d4];
    r = make_float4(cv.x + po.x, cv.y + po.y, cv.z + po.z, cv.w + po.w);
  } else {
    const float4 pv = *(const float4*)&pe[((size_t)(b * NPATCHI + t - 1)) * DMODEL + d4];
    r = make_float4(pv.x + po.x, pv.y + po.y, pv.z + po.z, pv.w + po.w);
  }
  *(float4*)&h[(size_t)row * DMODEL + d4] = r;
}

// ---------------------------------------------------------------------
__global__ __launch_bounds__(256) void ln_k(
    const float* __restrict__ in, const float* __restrict__ sc,
    const float* __restrict__ bi, __bf16* __restrict__ out)
{
  const int w = threadIdx.x >> 6, lane = threadIdx.x & 63;
  const int row = blockIdx.x * 4 + w;
  const float* r = in + (size_t)row * DMODEL;
  float v[6], sum = 0.f, ss = 0.f;
#pragma unroll
  for (int j = 0; j < 6; ++j) {
    const float xv = r[lane + 64 * j];
    v[j] = xv; sum += xv; ss += xv * xv;
  }
#pragma unroll
  for (int m = 1; m < 64; m <<= 1) {
    sum += __shfl_xor(sum, m, 64);
    ss  += __shfl_xor(ss,  m, 64);
  }
  const float mean = sum * (1.f / 384.f);
  const float var  = ss * (1.f / 384.f) - mean * mean;
  const float rstd = rsqrtf(var + 1e-5f);
  __bf16* o = out + (size_t)row * DMODEL;
#pragma unroll
  for (int j = 0; j < 6; ++j) {
    const int col = lane + 64 * j;
    o[col] = (__bf16)((v[j] - mean) * rstd * sc[col] + bi[col]);
  }
}

// ---------------------------------------------------------------------
__global__ __launch_bounds__(256) void sumsq_k(
    const __bf16* __restrict__ qkv, float* __restrict__ sq2,
    float* __restrict__ sk2)
{
  const int w = threadIdx.x >> 6, lane = threadIdx.x & 63;
  const int row = blockIdx.x * 4 + w;
  const int h = lane >> 4, lg = lane & 15;
  const __bf16* q = qkv + (size_t)row * 1152 + h * HDIM;
  float s1 = 0.f, s2 = 0.f;
#pragma unroll
  for (int j = 0; j < 6; ++j) {
    const float a = (float)q[lg + 16 * j];
    const float c = (float)q[384 + lg + 16 * j];
    s1 += a * a; s2 += c * c;
  }
#pragma unroll
  for (int m = 1; m < 16; m <<= 1) {
    s1 += __shfl_xor(s1, m, 64);
    s2 += __shfl_xor(s2, m, 64);
  }
  if (lg == 0) {
    const int b = row / TSEQ, t = row - b * TSEQ;
    sq2[((size_t)b * NHEAD + h) * TSEQ + t] = s1;
    sk2[((size_t)b * NHEAD + h) * TSEQ + t] = s2;
  }
}

// ---------------------------------------------------------------------
__global__ __launch_bounds__(256) void head_k(
    const float* __restrict__ h, const float* __restrict__ gs,
    const float* __restrict__ gb, const float* __restrict__ pw,
    const float* __restrict__ pb, const int* __restrict__ tgt,
    float* __restrict__ out)
{
  __shared__ float lg[BATCH][2];
  const int w = threadIdx.x >> 6, lane = threadIdx.x & 63;
  for (int b = w; b < BATCH; b += 4) {
    const float* r = h + (size_t)b * TSEQ * DMODEL;
    float v[6], sum = 0.f, ss = 0.f;
#pragma unroll
    for (int j = 0; j < 6; ++j) {
      const float xv = r[lane + 64 * j];
      v[j] = xv; sum += xv; ss += xv * xv;
    }
#pragma unroll
    for (int m = 1; m < 64; m <<= 1) {
      sum += __shfl_xor(sum, m, 64);
      ss  += __shfl_xor(ss,  m, 64);
    }
    const float mean = sum * (1.f / 384.f);
    const float var  = ss * (1.f / 384.f) - mean * mean;
    const float rstd = rsqrtf(var + 1e-5f);
    float l0 = 0.f, l1 = 0.f;
#pragma unroll
    for (int j = 0; j < 6; ++j) {
      const int col = lane + 64 * j;
      const float hnv = (v[j] - mean) * rstd * gs[col] + gb[col];
      l0 = fmaf(hnv, pw[col * 2 + 0], l0);
      l1 = fmaf(hnv, pw[col * 2 + 1], l1);
    }
#pragma unroll
    for (int m = 1; m < 64; m <<= 1) {
      l0 += __shfl_xor(l0, m, 64);
      l1 += __shfl_xor(l1, m, 64);
    }
    if (lane == 0) { lg[b][0] = l0 + pb[0]; lg[b][1] = l1 + pb[1]; }
  }
  __syncthreads();
  if (threadIdx.x < 32)
    out[threadIdx.x] = lg[threadIdx.x >> 1][threadIdx.x & 1];
  if (threadIdx.x == 0) {
    float acc = 0.f;
    for (int b = 0; b < BATCH; ++b) {
      const float a = lg[b][0], c = lg[b][1];
      const float mx = fmaxf(a, c);
      const float lse = mx + logf(expf(a - mx) + expf(c - mx));
      const float lp = ((tgt[b] == 0) ? a : c) - lse;
      acc += lp;
    }
    out[32] = -acc * (1.f / BATCH);
  }
}

// ---------------------------------------------------------------------
extern "C" void kernel_launch(void* const* d_in, const int* in_sizes, int n_in,
                              void* d_out, int out_size, void* d_ws, size_t ws_size,
                              hipStream_t stream)
{
  const float* x       = (const float*)d_in[0];
  const int*   targets = (const int*)  d_in[1];
  const float* conv_w  = (const float*)d_in[2];
  const float* conv_b  = (const float*)d_in[3];
  const float* cls_tok = (const float*)d_in[4];
  const float* pos_emb = (const float*)d_in[5];
  const float* ln1_s   = (const float*)d_in[6];
  const float* ln1_b   = (const float*)d_in[7];
  const float* ln2_s   = (const float*)d_in[8];
  const float* ln2_b   = (const float*)d_in[9];
  const float* wq      = (const float*)d_in[10];
  const float* wk      = (const float*)d_in[11];
  const float* wv      = (const float*)d_in[12];
  const float* wo      = (const float*)d_in[13];
  const float* bo      = (const float*)d_in[14];
  const float* w1      = (const float*)d_in[15];
  const float* b1      = (const float*)d_in[16];
  const float* w2      = (const float*)d_in[17];
  const float* b2      = (const float*)d_in[18];
  const float* lnf_s   = (const float*)d_in[19];
  const float* lnf_b   = (const float*)d_in[20];
  const float* proj_w  = (const float*)d_in[21];
  const float* proj_b  = (const float*)d_in[22];

  char* p = (char*)d_ws;
  auto alloc = [&](size_t bytes) -> void* {
    void* r = (void*)p; p += (bytes + 255) & ~(size_t)255; return r;
  };
  float*  h     = (float*) alloc((size_t)MROWS * DMODEL * 4);
  __bf16* hn    = (__bf16*)alloc((size_t)MROWS * DMODEL * 2);
  __bf16* qkv   = (__bf16*)alloc((size_t)MROWS * 1152 * 2);
  __bf16* Obuf  = (__bf16*)alloc((size_t)MROWS * DMODEL * 2);
  float*  pe    = (float*) alloc((size_t)MPATCH * DMODEL * 4);    // 25.17 MB
  float*  sq2   = (float*) alloc((size_t)BATCH * NHEAD * TSEQ * 4);
  float*  sk2   = (float*) alloc((size_t)BATCH * NHEAD * TSEQ * 4);
  __bf16* cwb   = (__bf16*)alloc((size_t)DMODEL * KPE * 2);
  __bf16* wqkvT = (__bf16*)alloc((size_t)NBLK * 1152 * DMODEL * 2);
  __bf16* woT   = (__bf16*)alloc((size_t)NBLK * DMODEL * DMODEL * 2);
  __bf16* w1T   = (__bf16*)alloc((size_t)NBLK * FFDIM * DMODEL * 2);
  __bf16* w2T   = (__bf16*)alloc((size_t)NBLK * DMODEL * FFDIM * 2);
  if ((size_t)(p - (char*)d_ws) > ws_size) return;
  __bf16* Ai  = qkv;           // im2col buffer, dead before QKV
  __bf16* ffb = qkv;           // MLP hidden spans qkv+Obuf exactly
  __bf16* Vtg = (__bf16*)pe;   // Vt[64][96][1088] = 13.37 MB <= pe (25.17 MB);
                               // pe is dead after embed_k.

  // ---- weight conversion ----
  cvt_k<<<144, 256, 0, stream>>>(conv_w, cwb, (DMODEL * KPE) / 8);
  {
    dim3 blk(32, 8);
    wt_k<<<dim3(12, 12, 3), blk, 0, stream>>>(wq, (size_t)DMODEL * DMODEL,
        wqkvT + 0,               (size_t)1152 * DMODEL, DMODEL, DMODEL);
    wt_k<<<dim3(12, 12, 3), blk, 0, stream>>>(wk, (size_t)DMODEL * DMODEL,
        wqkvT + 384 * DMODEL,    (size_t)1152 * DMODEL, DMODEL, DMODEL);
    wt_k<<<dim3(12, 12, 3), blk, 0, stream>>>(wv, (size_t)DMODEL * DMODEL,
        wqkvT + 768 * DMODEL,    (size_t)1152 * DMODEL, DMODEL, DMODEL);
    wt_k<<<dim3(12, 12, 3), blk, 0, stream>>>(wo, (size_t)DMODEL * DMODEL,
        woT, (size_t)DMODEL * DMODEL, DMODEL, DMODEL);
    wt_k<<<dim3(12, 48, 3), blk, 0, stream>>>(w1, (size_t)DMODEL * FFDIM,
        w1T, (size_t)FFDIM * DMODEL, DMODEL, FFDIM);
    wt_k<<<dim3(48, 12, 3), blk, 0, stream>>>(w2, (size_t)FFDIM * DMODEL,
        w2T, (size_t)DMODEL * FFDIM, FFDIM, DMODEL);
  }

  // ---- patch embedding ----
  im2col_k<<<6144, 256, 0, stream>>>(x, Ai);
  mgemm_k<9><<<dim3(128, 3), 256, 0, stream>>>(
      Ai, cwb, conv_b, nullptr, pe, nullptr, MPATCH, DMODEL, KPE);
  embed_k<<<6150, 256, 0, stream>>>(pe, cls_tok, pos_emb, h);

  // ---- transformer blocks ----
  for (int i = 0; i < NBLK; ++i) {
    ln_k<<<4100, 256, 0, stream>>>(h, ln1_s + i * DMODEL, ln1_b + i * DMODEL, hn);
    mgemm_k<16><<<dim3(129, 9), 256, 0, stream>>>(
        hn, wqkvT + (size_t)i * 1152 * DMODEL, nullptr, nullptr,
        nullptr, qkv, MROWS, 1152, DMODEL);
    sumsq_k<<<4100, 256, 0, stream>>>(qkv, sq2, sk2);
    vtr_k<<<dim3(34, 3, 64), dim3(32, 8), 0, stream>>>(qkv, Vtg);
    attn_k<<<dim3(17, 64), 256, 0, stream>>>(qkv, Vtg, sq2, sk2, Obuf);
    mgemm_k<13><<<dim3(129, 3), 256, 0, stream>>>(
        Obuf, woT + (size_t)i * DMODEL * DMODEL, bo + i * DMODEL, h,
        h, nullptr, MROWS, DMODEL, DMODEL);
    ln_k<<<4100, 256, 0, stream>>>(h, ln2_s + i * DMODEL, ln2_b + i * DMODEL, hn);
    mgemm_k<19><<<dim3(129, 12), 256, 0, stream>>>(
        hn, w1T + (size_t)i * FFDIM * DMODEL, b1 + i * FFDIM, nullptr,
        nullptr, ffb, MROWS, FFDIM, DMODEL);
    mgemm_k<13><<<dim3(129, 3), 256, 0, stream>>>(
        ffb, w2T + (size_t)i * DMODEL * FFDIM, b2 + i * DMODEL, h,
        h, nullptr, MROWS, DMODEL, FFDIM);
  }

  // ---- head ----
  head_k<<<1, 256, 0, stream>>>(h, lnf_s, lnf_b, proj_w, proj_b, targets,
                                (float*)d_out);
}